// Round 23
// baseline (137.829 us; speedup 1.0000x reference)
//
#include <hip/hip_runtime.h>

#define DEV __device__ __forceinline__

typedef __attribute__((ext_vector_type(8))) short short8;
typedef __attribute__((ext_vector_type(4))) float f32x4;
typedef unsigned short u16;
typedef unsigned int u32;

DEV f32x4 mfma16(short8 a, short8 b, f32x4 c) {
    return __builtin_amdgcn_mfma_f32_16x16x32_bf16(a, b, c, 0, 0, 0);
}

DEV u16 f2bf(float f) {
    unsigned u = __builtin_bit_cast(unsigned, f);
    u += 0x7fffu + ((u >> 16) & 1u);
    return (u16)(u >> 16);
}

// packed f32x2 -> bf16x2 (RNE), lo = a, hi = b
DEV u32 cvt_pk_bf16(float a, float b) {
    u32 r;
    asm("v_cvt_pk_bf16_f32 %0, %1, %2" : "=v"(r) : "v"(a), "v"(b));
    return r;
}

// Schraudolph exp2 on PRE-SCALED input x' = x * 2^23 (scale folded into Q).
DEV float fexp2_scaled(float xs) {
    int i = (int)xs + 1065055420;
    return __builtin_bit_cast(float, i);
}

DEV void gload16(const void* g, const void* l) {
    __builtin_amdgcn_global_load_lds(
        (const __attribute__((address_space(1))) unsigned int*)g,
        (__attribute__((address_space(3))) unsigned int*)l, 16, 0, 0);
}

template<int N> DEV void waitvm_barrier() {
    asm volatile("s_waitcnt vmcnt(%0)\n\ts_barrier" :: "n"(N) : "memory");
}

// swizzled b128 LDS fragment read: [rows][64] bf16 linear, 16B-chunk XOR (row&7)
DEV short8 lds_frag_swz(const u16* base, int row, int chunk) {
    int sc = chunk ^ (row & 7);
    return *(const short8*)((const char*)base + row * 128 + sc * 16);
}

// ---------------------------------------------------------------------------
// prep: weights only, f32 -> bf16 (4 x 576 blocks, ~2.5 us)
// ---------------------------------------------------------------------------
__global__ __launch_bounds__(256) void prep(
    const float* __restrict__ wq, const float* __restrict__ wk,
    const float* __restrict__ wv, const float* __restrict__ wo,
    u16* __restrict__ wqB, u16* __restrict__ wkB, u16* __restrict__ wvB,
    u16* __restrict__ woB)
{
    int b = blockIdx.x;
    int t = b / 576, r = b % 576;
    const float* s = t == 0 ? wq : t == 1 ? wk : t == 2 ? wv : wo;
    u16* d = t == 0 ? wqB : t == 1 ? wkB : t == 2 ? wvB : woB;
    int i = r * 256 + threadIdx.x;
    float4 vv = ((const float4*)s)[i];
    ((ushort4*)d)[i] = make_ushort4(f2bf(vv.x), f2bf(vv.y), f2bf(vv.z), f2bf(vv.w));
}

// ---------------------------------------------------------------------------
// GEMM: tile 64M x 128N, BK=64.  Operands: bf16 plane via swizzled gload_lds,
// or f32 via in-register cvt_pk (RNE, bit-identical to prep's f2bf) +
// swizzled ds_write.  LDS buffers passed in (one 24 KB allocation shared by
// all inlined instantiations -- R21 fix).
// MODE 0: head plane [bh][s][d] u16; MODE 1: f32 [M][768];
// MODE 2: V^T plane [bh][d][s] u16 (bias by row).
// ---------------------------------------------------------------------------
template<int AF32, int BF32, int MODE>
DEV void gemm_body(u16* __restrict__ AS, u16* __restrict__ BS,
                   const float* __restrict__ Af, const u16* __restrict__ A_g,
                   const float* __restrict__ Bf, const u16* __restrict__ B_g,
                   const float* __restrict__ bias, float scale,
                   u16* __restrict__ outP, float* __restrict__ outF,
                   int mBase, int nBase)
{
    const int tid = threadIdx.x;
    const int l = tid & 63, wid = tid >> 6;
    const int wy = wid >> 1, wx = wid & 1;    // wave tile: 32M x 64N
    const int lr = l & 15, lg = l >> 4;

    f32x4 acc[2][4];
    for (int i = 0; i < 2; ++i)
        for (int j = 0; j < 4; ++j) acc[i][j] = (f32x4)0.0f;

    for (int kt = 0; kt < 12; ++kt) {
        if (kt) __syncthreads();
        // ---- stage A (64 rows x 64 k) ----
        if constexpr (AF32) {
            for (int i = 0; i < 4; ++i) {
                int f = tid + i * 256;                // float4-chunk id, 0..1023
                int row = f >> 4, q4 = f & 15;
                float4 xv = *(const float4*)(Af + (size_t)(mBase + row) * 768 + kt * 64 + q4 * 4);
                u32 lo = cvt_pk_bf16(xv.x, xv.y);
                u32 hi = cvt_pk_bf16(xv.z, xv.w);
                int byteOff = row * 128 + (((q4 >> 1) ^ (row & 7)) * 16) + (q4 & 1) * 8;
                *(uint2*)((char*)AS + byteOff) = make_uint2(lo, hi);
            }
        } else {
            for (int r = 0; r < 2; ++r) {
                int c = tid + r * 256;
                int row = c >> 3;
                int sc = (c & 7) ^ (row & 7);
                size_t gA = (size_t)(mBase + row) * 768 + kt * 64 + sc * 8;
                gload16(A_g + gA, AS + (size_t)(r * 256 + wid * 64) * 8);
            }
        }
        // ---- stage B (128 rows x 64 k) ----
        if constexpr (BF32) {
            for (int i = 0; i < 8; ++i) {
                int f = tid + i * 256;                // 0..2047
                int row = f >> 4, q4 = f & 15;
                float4 xv = *(const float4*)(Bf + (size_t)(nBase + row) * 768 + kt * 64 + q4 * 4);
                u32 lo = cvt_pk_bf16(xv.x, xv.y);
                u32 hi = cvt_pk_bf16(xv.z, xv.w);
                int byteOff = row * 128 + (((q4 >> 1) ^ (row & 7)) * 16) + (q4 & 1) * 8;
                *(uint2*)((char*)BS + byteOff) = make_uint2(lo, hi);
            }
        } else {
            for (int r = 0; r < 4; ++r) {
                int c = tid + r * 256;
                int row = c >> 3;
                int sc = (c & 7) ^ (row & 7);
                size_t gB = (size_t)(nBase + row) * 768 + kt * 64 + sc * 8;
                gload16(B_g + gB, BS + (size_t)(r * 256 + wid * 64) * 8);
            }
        }
        __syncthreads();   // drains vmcnt + lgkmcnt

        short8 bf[4][2];
        for (int nt = 0; nt < 4; ++nt)
            for (int ks = 0; ks < 2; ++ks)
                bf[nt][ks] = lds_frag_swz(BS, wx * 64 + nt * 16 + lr, ks * 4 + lg);
        for (int mt = 0; mt < 2; ++mt) {
            short8 ah[2];
            for (int ks = 0; ks < 2; ++ks)
                ah[ks] = lds_frag_swz(AS, wy * 32 + mt * 16 + lr, ks * 4 + lg);
            for (int nt = 0; nt < 4; ++nt)
                for (int ks = 0; ks < 2; ++ks)
                    acc[mt][nt] = mfma16(ah[ks], bf[nt][ks], acc[mt][nt]);
        }
    }

    for (int mt = 0; mt < 2; ++mt)
        for (int nt = 0; nt < 4; ++nt) {
            int colg = nBase + wx * 64 + nt * 16 + lr;
            for (int r = 0; r < 4; ++r) {
                int rowg = mBase + wy * 32 + mt * 16 + lg * 4 + r;
                float bv = (MODE == 2) ? bias[rowg] : bias[colg];
                float vv = (acc[mt][nt][r] + bv) * scale;
                if constexpr (MODE == 0) {
                    int b = rowg >> 11, s = rowg & 2047;
                    int h = colg >> 6, d = colg & 63;
                    outP[((size_t)(b * 12 + h) * 2048 + s) * 64 + d] = f2bf(vv);
                } else if constexpr (MODE == 1) {
                    outF[(size_t)rowg * 768 + colg] = vv;
                } else {
                    int b = colg >> 11, s = colg & 2047;
                    int h = rowg >> 6, d = rowg & 63;
                    outP[((size_t)(b * 12 + h) * 64 + d) * 2048 + s] = f2bf(vv);
                }
            }
        }
}

// ---------------------------------------------------------------------------
// fused Q/K/V projections; inputs stay f32.  XCD-colocating block map
// (R19-verified: FETCH 233 -> 51 MB): linear id b -> XCD b%8, blocks sharing
// an input stripe sit 8 apart -> same XCD's L2.
// ---------------------------------------------------------------------------
__global__ __launch_bounds__(256, 4) void gemm_proj(
    const float* __restrict__ q, const float* __restrict__ k, const float* __restrict__ v,
    const u16* __restrict__ wqB, const u16* __restrict__ wkB, const u16* __restrict__ wvB,
    const float* __restrict__ bq, const float* __restrict__ bk, const float* __restrict__ bv,
    u16* __restrict__ Qpl, u16* __restrict__ Kpl, u16* __restrict__ Vtp)
{
    __shared__ u16 AS[64 * 64], BS[128 * 64];
    int b = blockIdx.x;           // 0..767
    int z = blockIdx.z;
    if (z < 2) {
        int m = (b & 7) + 8 * ((b >> 3) / 6);
        int n = (b >> 3) % 6;
        if (z == 0) {
            gemm_body<1, 0, 0>(AS, BS, q, nullptr, nullptr, wqB, bq,
                               0.125f * 1.44269504f * 8388608.0f, Qpl, nullptr,
                               m * 64, n * 128);
        } else {
            gemm_body<1, 0, 0>(AS, BS, k, nullptr, nullptr, wkB, bk, 1.0f, Kpl, nullptr,
                               m * 64, n * 128);
        }
    } else {
        int m = (b >> 3) % 12;
        int n = (b & 7) + 8 * ((b >> 3) / 12);
        gemm_body<0, 1, 2>(AS, BS, nullptr, wvB, v, nullptr, bv, 1.0f, Vtp, nullptr,
                           m * 64, n * 128);
    }
}

// ---------------------------------------------------------------------------
// final projection: Op bf16 x woB bf16 -> f32 out.  XCD-colocating map
// (R22-verified): all 6 n-blocks sharing an A stripe share b&7 -> one XCD.
// ---------------------------------------------------------------------------
__global__ __launch_bounds__(256, 4) void gemm_out(
    const u16* __restrict__ Op, const u16* __restrict__ woB,
    const float* __restrict__ bias, float* __restrict__ outF)
{
    __shared__ u16 AS[64 * 64], BS[128 * 64];
    int b = blockIdx.x;           // 0..767
    int m = (b & 7) + 8 * ((b >> 3) / 6);
    int n = (b >> 3) % 6;
    gemm_body<0, 0, 1>(AS, BS, nullptr, Op, nullptr, woB, bias, 1.0f, nullptr, outF,
                       m * 64, n * 128);
}

// ---------------------------------------------------------------------------
// Attention: R17/R10 kernel, setprio REMOVED (m190: setprio hurts
// barrier-synced lockstep kernels; attn4 has been 4-wave lockstep since R10 —
// the setprio was added in R6's loosely-phased 8-wave version and never
// re-isolated).  Everything else identical to R22: 4 waves x 32 q-rows,
// KVBLK=64, E tile [128][72] padded + uint2 writes, K/V [64][64] XOR(row&7),
// double-buffered K/V, one vmcnt(0)+barrier per iter, swapped QK^T,
// Schraudolph exp2 (pre-scaled in Q), den via ones-MFMA from the same E.
// ---------------------------------------------------------------------------
__global__ __launch_bounds__(256, 3) void attn4(
    const u16* __restrict__ Qp, const u16* __restrict__ Kp,
    const u16* __restrict__ Vtp, u16* __restrict__ Op)
{
    __shared__ u16 Ks[2][64 * 64], Vs[2][64 * 64];
    __shared__ u16 Eh[128][72];

    const int tid = threadIdx.x;
    const int l = tid & 63, wid = tid >> 6;     // 4 waves
    const int lr = l & 15, lg = l >> 4;
    const int bh = blockIdx.x, qt = blockIdx.y;

    short8 q_h[2][2];
    for (int s = 0; s < 2; ++s) {
        size_t qrow = ((size_t)bh * 2048 + qt * 128 + wid * 32 + s * 16 + lr) * 64;
        q_h[s][0] = *(const short8*)(Qp + qrow + lg * 8);
        q_h[s][1] = *(const short8*)(Qp + qrow + 32 + lg * 8);
    }

    short8 ones;
    for (int j = 0; j < 8; ++j) ones[j] = (short)0x3F80;  // bf16 1.0

    f32x4 num[2][4];
    for (int s = 0; s < 2; ++s)
        for (int nt = 0; nt < 4; ++nt) num[s][nt] = (f32x4)0.0f;
    f32x4 denacc[2] = {(f32x4)0.0f, (f32x4)0.0f};

    auto stageK = [&](int kb, int p) {
        for (int r = 0; r < 2; ++r) {
            int c = tid + r * 256;
            int row = c >> 3, sc = (c & 7) ^ (row & 7);
            size_t g = ((size_t)bh * 2048 + kb * 64 + row) * 64 + sc * 8;
            gload16(Kp + g, Ks[p] + (size_t)(r * 256 + wid * 64) * 8);
        }
    };
    auto stageV = [&](int kb, int p) {
        for (int r = 0; r < 2; ++r) {
            int c = tid + r * 256;
            int row = c >> 3, sc = (c & 7) ^ (row & 7);
            size_t g = ((size_t)bh * 64 + row) * 2048 + kb * 64 + sc * 8;
            gload16(Vtp + g, Vs[p] + (size_t)(r * 256 + wid * 64) * 8);
        }
    };

    stageK(0, 0);
    stageV(0, 0);

    for (int kb = 0; kb < 32; ++kb) {
        const int p = kb & 1;
        waitvm_barrier<0>();
        if (kb < 31) {
            stageK(kb + 1, p ^ 1);
            stageV(kb + 1, p ^ 1);
        }

        f32x4 st[2][4];
        for (int s = 0; s < 2; ++s)
            for (int nt = 0; nt < 4; ++nt) st[s][nt] = (f32x4)0.0f;
        for (int nt = 0; nt < 4; ++nt)
            for (int ks = 0; ks < 2; ++ks) {
                short8 kh = lds_frag_swz(Ks[p], nt * 16 + lr, ks * 4 + lg);
                st[0][nt] = mfma16(kh, q_h[0][ks], st[0][nt]);
                st[1][nt] = mfma16(kh, q_h[1][ks], st[1][nt]);
            }

        for (int s = 0; s < 2; ++s)
            for (int nt = 0; nt < 4; ++nt) {
                u32 pk0 = cvt_pk_bf16(fexp2_scaled(st[s][nt][0]), fexp2_scaled(st[s][nt][1]));
                u32 pk1 = cvt_pk_bf16(fexp2_scaled(st[s][nt][2]), fexp2_scaled(st[s][nt][3]));
                int erow = wid * 32 + s * 16 + lr;
                *(uint2*)&Eh[erow][nt * 16 + lg * 4] = make_uint2(pk0, pk1);
            }

        short8 e[2][2];
        for (int s = 0; s < 2; ++s) {
            int erow = wid * 32 + s * 16 + lr;
            e[s][0] = *(const short8*)&Eh[erow][lg * 8];
            e[s][1] = *(const short8*)&Eh[erow][32 + lg * 8];
        }
        denacc[0] = mfma16(e[0][0], ones, denacc[0]);
        denacc[0] = mfma16(e[0][1], ones, denacc[0]);
        denacc[1] = mfma16(e[1][0], ones, denacc[1]);
        denacc[1] = mfma16(e[1][1], ones, denacc[1]);
        for (int nt = 0; nt < 4; ++nt)
            for (int ks = 0; ks < 2; ++ks) {
                short8 vh = lds_frag_swz(Vs[p], nt * 16 + lr, ks * 4 + lg);
                num[0][nt] = mfma16(e[0][ks], vh, num[0][nt]);
                num[1][nt] = mfma16(e[1][ks], vh, num[1][nt]);
            }
    }

    const int b = bh / 12, h = bh % 12;
    for (int s = 0; s < 2; ++s) {
        float rden[4];
        for (int r = 0; r < 4; ++r) rden[r] = 1.0f / denacc[s][r];
        for (int nt = 0; nt < 4; ++nt)
            for (int r = 0; r < 4; ++r) {
                int srow = qt * 128 + wid * 32 + s * 16 + lg * 4 + r;
                size_t rowg = (size_t)b * 2048 + srow;
                int col = h * 64 + nt * 16 + lr;
                Op[rowg * 768 + col] = f2bf(num[s][nt][r] * rden[r]);
            }
    }
}

extern "C" void kernel_launch(void* const* d_in, const int* in_sizes, int n_in,
                              void* d_out, int out_size, void* d_ws, size_t ws_size,
                              hipStream_t stream)
{
    const float* q   = (const float*)d_in[0];
    const float* k   = (const float*)d_in[1];
    const float* v   = (const float*)d_in[2];
    const float* w_q = (const float*)d_in[3];
    const float* b_q = (const float*)d_in[4];
    const float* w_k = (const float*)d_in[5];
    const float* b_k = (const float*)d_in[6];
    const float* w_v = (const float*)d_in[7];
    const float* b_v = (const float*)d_in[8];
    const float* w_o = (const float*)d_in[9];
    const float* b_o = (const float*)d_in[10];
    float* out = (float*)d_out;

    const size_t PL  = (size_t)48 * 2048 * 64;   // 6291456 elems (= 8192*768)
    const size_t WPL = (size_t)768 * 768;
    u16* base = (u16*)d_ws;
    u16* Qpl = base;                 // [bh][s][d]
    u16* Kpl = base + PL;
    u16* Vtp = base + 2 * PL;        // [bh][d][s]
    u16* OP  = base + 3 * PL;        // attn out [8192][768] bf16
    u16* W   = base + 4 * PL;
    u16* wqB = W;
    u16* wkB = W + WPL;
    u16* wvB = W + 2 * WPL;
    u16* woB = W + 3 * WPL;

    dim3 bt(256, 1, 1);
    hipLaunchKernelGGL(prep, dim3(2304), bt, 0, stream,
                       w_q, w_k, w_v, w_o, wqB, wkB, wvB, woB);

    hipLaunchKernelGGL(gemm_proj, dim3(768, 1, 3), bt, 0, stream,
                       q, k, v, wqB, wkB, wvB, b_q, b_k, b_v,
                       Qpl, Kpl, Vtp);

    hipLaunchKernelGGL(attn4, dim3(48, 16), bt, 0, stream,
                       Qpl, Kpl, Vtp, OP);

    hipLaunchKernelGGL(gemm_out, dim3(768), bt, 0, stream,
                       OP, woB, b_o, out);
}

// Round 24
// 136.326 us; speedup vs baseline: 1.0110x; 1.0110x over previous
//
#include <hip/hip_runtime.h>

#define DEV __device__ __forceinline__

typedef __attribute__((ext_vector_type(8))) short short8;
typedef __attribute__((ext_vector_type(4))) float f32x4;
typedef unsigned short u16;
typedef unsigned int u32;

DEV f32x4 mfma16(short8 a, short8 b, f32x4 c) {
    return __builtin_amdgcn_mfma_f32_16x16x32_bf16(a, b, c, 0, 0, 0);
}

DEV u16 f2bf(float f) {
    unsigned u = __builtin_bit_cast(unsigned, f);
    u += 0x7fffu + ((u >> 16) & 1u);
    return (u16)(u >> 16);
}

// packed f32x2 -> bf16x2 (RNE), lo = a, hi = b
DEV u32 cvt_pk_bf16(float a, float b) {
    u32 r;
    asm("v_cvt_pk_bf16_f32 %0, %1, %2" : "=v"(r) : "v"(a), "v"(b));
    return r;
}

// Schraudolph exp2 on PRE-SCALED input x' = x * 2^23 (scale folded into Q).
DEV float fexp2_scaled(float xs) {
    int i = (int)xs + 1065055420;
    return __builtin_bit_cast(float, i);
}

DEV void gload16(const void* g, const void* l) {
    __builtin_amdgcn_global_load_lds(
        (const __attribute__((address_space(1))) unsigned int*)g,
        (__attribute__((address_space(3))) unsigned int*)l, 16, 0, 0);
}

template<int N> DEV void waitvm_barrier() {
    asm volatile("s_waitcnt vmcnt(%0)\n\ts_barrier" :: "n"(N) : "memory");
}

// swizzled b128 LDS fragment read: [rows][64] bf16 linear, 16B-chunk XOR (row&7)
DEV short8 lds_frag_swz(const u16* base, int row, int chunk) {
    int sc = chunk ^ (row & 7);
    return *(const short8*)((const char*)base + row * 128 + sc * 16);
}

// ---------------------------------------------------------------------------
// prep: weights only, f32 -> bf16 (4 x 576 blocks, ~2.5 us)
// ---------------------------------------------------------------------------
__global__ __launch_bounds__(256) void prep(
    const float* __restrict__ wq, const float* __restrict__ wk,
    const float* __restrict__ wv, const float* __restrict__ wo,
    u16* __restrict__ wqB, u16* __restrict__ wkB, u16* __restrict__ wvB,
    u16* __restrict__ woB)
{
    int b = blockIdx.x;
    int t = b / 576, r = b % 576;
    const float* s = t == 0 ? wq : t == 1 ? wk : t == 2 ? wv : wo;
    u16* d = t == 0 ? wqB : t == 1 ? wkB : t == 2 ? wvB : woB;
    int i = r * 256 + threadIdx.x;
    float4 vv = ((const float4*)s)[i];
    ((ushort4*)d)[i] = make_ushort4(f2bf(vv.x), f2bf(vv.y), f2bf(vv.z), f2bf(vv.w));
}

// ---------------------------------------------------------------------------
// GEMM: tile 64M x 128N, BK=64.  Operands: bf16 plane via swizzled gload_lds,
// or f32 via in-register cvt_pk (RNE, bit-identical to prep's f2bf) +
// swizzled ds_write.  LDS buffers passed in (one 24 KB allocation shared by
// all inlined instantiations -- R21 fix).
// MODE 0: head plane [bh][s][d] u16; MODE 1: f32 [M][768];
// MODE 2: V^T plane [bh][d][s] u16 (bias by row).
// ---------------------------------------------------------------------------
template<int AF32, int BF32, int MODE>
DEV void gemm_body(u16* __restrict__ AS, u16* __restrict__ BS,
                   const float* __restrict__ Af, const u16* __restrict__ A_g,
                   const float* __restrict__ Bf, const u16* __restrict__ B_g,
                   const float* __restrict__ bias, float scale,
                   u16* __restrict__ outP, float* __restrict__ outF,
                   int mBase, int nBase)
{
    const int tid = threadIdx.x;
    const int l = tid & 63, wid = tid >> 6;
    const int wy = wid >> 1, wx = wid & 1;    // wave tile: 32M x 64N
    const int lr = l & 15, lg = l >> 4;

    f32x4 acc[2][4];
    for (int i = 0; i < 2; ++i)
        for (int j = 0; j < 4; ++j) acc[i][j] = (f32x4)0.0f;

    for (int kt = 0; kt < 12; ++kt) {
        if (kt) __syncthreads();
        // ---- stage A (64 rows x 64 k) ----
        if constexpr (AF32) {
            for (int i = 0; i < 4; ++i) {
                int f = tid + i * 256;                // float4-chunk id, 0..1023
                int row = f >> 4, q4 = f & 15;
                float4 xv = *(const float4*)(Af + (size_t)(mBase + row) * 768 + kt * 64 + q4 * 4);
                u32 lo = cvt_pk_bf16(xv.x, xv.y);
                u32 hi = cvt_pk_bf16(xv.z, xv.w);
                int byteOff = row * 128 + (((q4 >> 1) ^ (row & 7)) * 16) + (q4 & 1) * 8;
                *(uint2*)((char*)AS + byteOff) = make_uint2(lo, hi);
            }
        } else {
            for (int r = 0; r < 2; ++r) {
                int c = tid + r * 256;
                int row = c >> 3;
                int sc = (c & 7) ^ (row & 7);
                size_t gA = (size_t)(mBase + row) * 768 + kt * 64 + sc * 8;
                gload16(A_g + gA, AS + (size_t)(r * 256 + wid * 64) * 8);
            }
        }
        // ---- stage B (128 rows x 64 k) ----
        if constexpr (BF32) {
            for (int i = 0; i < 8; ++i) {
                int f = tid + i * 256;                // 0..2047
                int row = f >> 4, q4 = f & 15;
                float4 xv = *(const float4*)(Bf + (size_t)(nBase + row) * 768 + kt * 64 + q4 * 4);
                u32 lo = cvt_pk_bf16(xv.x, xv.y);
                u32 hi = cvt_pk_bf16(xv.z, xv.w);
                int byteOff = row * 128 + (((q4 >> 1) ^ (row & 7)) * 16) + (q4 & 1) * 8;
                *(uint2*)((char*)BS + byteOff) = make_uint2(lo, hi);
            }
        } else {
            for (int r = 0; r < 4; ++r) {
                int c = tid + r * 256;
                int row = c >> 3;
                int sc = (c & 7) ^ (row & 7);
                size_t gB = (size_t)(nBase + row) * 768 + kt * 64 + sc * 8;
                gload16(B_g + gB, BS + (size_t)(r * 256 + wid * 64) * 8);
            }
        }
        __syncthreads();   // drains vmcnt + lgkmcnt

        short8 bf[4][2];
        for (int nt = 0; nt < 4; ++nt)
            for (int ks = 0; ks < 2; ++ks)
                bf[nt][ks] = lds_frag_swz(BS, wx * 64 + nt * 16 + lr, ks * 4 + lg);
        for (int mt = 0; mt < 2; ++mt) {
            short8 ah[2];
            for (int ks = 0; ks < 2; ++ks)
                ah[ks] = lds_frag_swz(AS, wy * 32 + mt * 16 + lr, ks * 4 + lg);
            for (int nt = 0; nt < 4; ++nt)
                for (int ks = 0; ks < 2; ++ks)
                    acc[mt][nt] = mfma16(ah[ks], bf[nt][ks], acc[mt][nt]);
        }
    }

    for (int mt = 0; mt < 2; ++mt)
        for (int nt = 0; nt < 4; ++nt) {
            int colg = nBase + wx * 64 + nt * 16 + lr;
            for (int r = 0; r < 4; ++r) {
                int rowg = mBase + wy * 32 + mt * 16 + lg * 4 + r;
                float bv = (MODE == 2) ? bias[rowg] : bias[colg];
                float vv = (acc[mt][nt][r] + bv) * scale;
                if constexpr (MODE == 0) {
                    int b = rowg >> 11, s = rowg & 2047;
                    int h = colg >> 6, d = colg & 63;
                    outP[((size_t)(b * 12 + h) * 2048 + s) * 64 + d] = f2bf(vv);
                } else if constexpr (MODE == 1) {
                    outF[(size_t)rowg * 768 + colg] = vv;
                } else {
                    int b = colg >> 11, s = colg & 2047;
                    int h = rowg >> 6, d = rowg & 63;
                    outP[((size_t)(b * 12 + h) * 64 + d) * 2048 + s] = f2bf(vv);
                }
            }
        }
}

// ---------------------------------------------------------------------------
// fused Q/K/V projections; inputs stay f32.  XCD-colocating block map
// (R19-verified: FETCH 233 -> 51 MB): linear id b -> XCD b%8, blocks sharing
// an input stripe sit 8 apart -> same XCD's L2.
// ---------------------------------------------------------------------------
__global__ __launch_bounds__(256, 4) void gemm_proj(
    const float* __restrict__ q, const float* __restrict__ k, const float* __restrict__ v,
    const u16* __restrict__ wqB, const u16* __restrict__ wkB, const u16* __restrict__ wvB,
    const float* __restrict__ bq, const float* __restrict__ bk, const float* __restrict__ bv,
    u16* __restrict__ Qpl, u16* __restrict__ Kpl, u16* __restrict__ Vtp)
{
    __shared__ u16 AS[64 * 64], BS[128 * 64];
    int b = blockIdx.x;           // 0..767
    int z = blockIdx.z;
    if (z < 2) {
        int m = (b & 7) + 8 * ((b >> 3) / 6);
        int n = (b >> 3) % 6;
        if (z == 0) {
            gemm_body<1, 0, 0>(AS, BS, q, nullptr, nullptr, wqB, bq,
                               0.125f * 1.44269504f * 8388608.0f, Qpl, nullptr,
                               m * 64, n * 128);
        } else {
            gemm_body<1, 0, 0>(AS, BS, k, nullptr, nullptr, wkB, bk, 1.0f, Kpl, nullptr,
                               m * 64, n * 128);
        }
    } else {
        int m = (b >> 3) % 12;
        int n = (b & 7) + 8 * ((b >> 3) / 12);
        gemm_body<0, 1, 2>(AS, BS, nullptr, wvB, v, nullptr, bv, 1.0f, Vtp, nullptr,
                           m * 64, n * 128);
    }
}

// ---------------------------------------------------------------------------
// final projection: Op bf16 x woB bf16 -> f32 out.  XCD-colocating map
// (R22-verified): all 6 n-blocks sharing an A stripe share b&7 -> one XCD.
// ---------------------------------------------------------------------------
__global__ __launch_bounds__(256, 4) void gemm_out(
    const u16* __restrict__ Op, const u16* __restrict__ woB,
    const float* __restrict__ bias, float* __restrict__ outF)
{
    __shared__ u16 AS[64 * 64], BS[128 * 64];
    int b = blockIdx.x;           // 0..767
    int m = (b & 7) + 8 * ((b >> 3) / 6);
    int n = (b >> 3) % 6;
    gemm_body<0, 0, 1>(AS, BS, nullptr, Op, nullptr, woB, bias, 1.0f, nullptr, outF,
                       m * 64, n * 128);
}

// ---------------------------------------------------------------------------
// Attention: R22-verified best (66.3 us): 4 waves x 32 q-rows, KVBLK=64,
// E tile [128][72] padded + uint2 writes, K/V [64][64] XOR(row&7),
// double-buffered K/V, one vmcnt(0)+barrier per iter, swapped QK^T,
// Schraudolph exp2 (pre-scaled in Q), den via ones-MFMA from the same E,
// setprio around MFMA clusters (R23 A/B: removal was -0.9%, restored).
// ---------------------------------------------------------------------------
__global__ __launch_bounds__(256, 3) void attn4(
    const u16* __restrict__ Qp, const u16* __restrict__ Kp,
    const u16* __restrict__ Vtp, u16* __restrict__ Op)
{
    __shared__ u16 Ks[2][64 * 64], Vs[2][64 * 64];
    __shared__ u16 Eh[128][72];

    const int tid = threadIdx.x;
    const int l = tid & 63, wid = tid >> 6;     // 4 waves
    const int lr = l & 15, lg = l >> 4;
    const int bh = blockIdx.x, qt = blockIdx.y;

    short8 q_h[2][2];
    for (int s = 0; s < 2; ++s) {
        size_t qrow = ((size_t)bh * 2048 + qt * 128 + wid * 32 + s * 16 + lr) * 64;
        q_h[s][0] = *(const short8*)(Qp + qrow + lg * 8);
        q_h[s][1] = *(const short8*)(Qp + qrow + 32 + lg * 8);
    }

    short8 ones;
    for (int j = 0; j < 8; ++j) ones[j] = (short)0x3F80;  // bf16 1.0

    f32x4 num[2][4];
    for (int s = 0; s < 2; ++s)
        for (int nt = 0; nt < 4; ++nt) num[s][nt] = (f32x4)0.0f;
    f32x4 denacc[2] = {(f32x4)0.0f, (f32x4)0.0f};

    auto stageK = [&](int kb, int p) {
        for (int r = 0; r < 2; ++r) {
            int c = tid + r * 256;
            int row = c >> 3, sc = (c & 7) ^ (row & 7);
            size_t g = ((size_t)bh * 2048 + kb * 64 + row) * 64 + sc * 8;
            gload16(Kp + g, Ks[p] + (size_t)(r * 256 + wid * 64) * 8);
        }
    };
    auto stageV = [&](int kb, int p) {
        for (int r = 0; r < 2; ++r) {
            int c = tid + r * 256;
            int row = c >> 3, sc = (c & 7) ^ (row & 7);
            size_t g = ((size_t)bh * 64 + row) * 2048 + kb * 64 + sc * 8;
            gload16(Vtp + g, Vs[p] + (size_t)(r * 256 + wid * 64) * 8);
        }
    };

    stageK(0, 0);
    stageV(0, 0);

    for (int kb = 0; kb < 32; ++kb) {
        const int p = kb & 1;
        waitvm_barrier<0>();
        if (kb < 31) {
            stageK(kb + 1, p ^ 1);
            stageV(kb + 1, p ^ 1);
        }

        f32x4 st[2][4];
        for (int s = 0; s < 2; ++s)
            for (int nt = 0; nt < 4; ++nt) st[s][nt] = (f32x4)0.0f;
        __builtin_amdgcn_s_setprio(1);
        for (int nt = 0; nt < 4; ++nt)
            for (int ks = 0; ks < 2; ++ks) {
                short8 kh = lds_frag_swz(Ks[p], nt * 16 + lr, ks * 4 + lg);
                st[0][nt] = mfma16(kh, q_h[0][ks], st[0][nt]);
                st[1][nt] = mfma16(kh, q_h[1][ks], st[1][nt]);
            }
        __builtin_amdgcn_s_setprio(0);

        for (int s = 0; s < 2; ++s)
            for (int nt = 0; nt < 4; ++nt) {
                u32 pk0 = cvt_pk_bf16(fexp2_scaled(st[s][nt][0]), fexp2_scaled(st[s][nt][1]));
                u32 pk1 = cvt_pk_bf16(fexp2_scaled(st[s][nt][2]), fexp2_scaled(st[s][nt][3]));
                int erow = wid * 32 + s * 16 + lr;
                *(uint2*)&Eh[erow][nt * 16 + lg * 4] = make_uint2(pk0, pk1);
            }

        short8 e[2][2];
        for (int s = 0; s < 2; ++s) {
            int erow = wid * 32 + s * 16 + lr;
            e[s][0] = *(const short8*)&Eh[erow][lg * 8];
            e[s][1] = *(const short8*)&Eh[erow][32 + lg * 8];
        }
        __builtin_amdgcn_s_setprio(1);
        denacc[0] = mfma16(e[0][0], ones, denacc[0]);
        denacc[0] = mfma16(e[0][1], ones, denacc[0]);
        denacc[1] = mfma16(e[1][0], ones, denacc[1]);
        denacc[1] = mfma16(e[1][1], ones, denacc[1]);
        for (int nt = 0; nt < 4; ++nt)
            for (int ks = 0; ks < 2; ++ks) {
                short8 vh = lds_frag_swz(Vs[p], nt * 16 + lr, ks * 4 + lg);
                num[0][nt] = mfma16(e[0][ks], vh, num[0][nt]);
                num[1][nt] = mfma16(e[1][ks], vh, num[1][nt]);
            }
        __builtin_amdgcn_s_setprio(0);
    }

    const int b = bh / 12, h = bh % 12;
    for (int s = 0; s < 2; ++s) {
        float rden[4];
        for (int r = 0; r < 4; ++r) rden[r] = 1.0f / denacc[s][r];
        for (int nt = 0; nt < 4; ++nt)
            for (int r = 0; r < 4; ++r) {
                int srow = qt * 128 + wid * 32 + s * 16 + lg * 4 + r;
                size_t rowg = (size_t)b * 2048 + srow;
                int col = h * 64 + nt * 16 + lr;
                Op[rowg * 768 + col] = f2bf(num[s][nt][r] * rden[r]);
            }
    }
}

extern "C" void kernel_launch(void* const* d_in, const int* in_sizes, int n_in,
                              void* d_out, int out_size, void* d_ws, size_t ws_size,
                              hipStream_t stream)
{
    const float* q   = (const float*)d_in[0];
    const float* k   = (const float*)d_in[1];
    const float* v   = (const float*)d_in[2];
    const float* w_q = (const float*)d_in[3];
    const float* b_q = (const float*)d_in[4];
    const float* w_k = (const float*)d_in[5];
    const float* b_k = (const float*)d_in[6];
    const float* w_v = (const float*)d_in[7];
    const float* b_v = (const float*)d_in[8];
    const float* w_o = (const float*)d_in[9];
    const float* b_o = (const float*)d_in[10];
    float* out = (float*)d_out;

    const size_t PL  = (size_t)48 * 2048 * 64;   // 6291456 elems (= 8192*768)
    const size_t WPL = (size_t)768 * 768;
    u16* base = (u16*)d_ws;
    u16* Qpl = base;                 // [bh][s][d]
    u16* Kpl = base + PL;
    u16* Vtp = base + 2 * PL;        // [bh][d][s]
    u16* OP  = base + 3 * PL;        // attn out [8192][768] bf16
    u16* W   = base + 4 * PL;
    u16* wqB = W;
    u16* wkB = W + WPL;
    u16* wvB = W + 2 * WPL;
    u16* woB = W + 3 * WPL;

    dim3 bt(256, 1, 1);
    hipLaunchKernelGGL(prep, dim3(2304), bt, 0, stream,
                       w_q, w_k, w_v, w_o, wqB, wkB, wvB, woB);

    hipLaunchKernelGGL(gemm_proj, dim3(768, 1, 3), bt, 0, stream,
                       q, k, v, wqB, wkB, wvB, b_q, b_k, b_v,
                       Qpl, Kpl, Vtp);

    hipLaunchKernelGGL(attn4, dim3(48, 16), bt, 0, stream,
                       Qpl, Kpl, Vtp, OP);

    hipLaunchKernelGGL(gemm_out, dim3(768), bt, 0, stream,
                       OP, woB, b_o, out);
}